// Round 1
// baseline (665.528 us; speedup 1.0000x reference)
//
#include <hip/hip_runtime.h>
#include <stdint.h>

typedef __bf16 bf16;
typedef __bf16 bf16x8 __attribute__((ext_vector_type(8)));
typedef float  f32x4  __attribute__((ext_vector_type(4)));

#define TSCALE 256
#define NS     32
#define C1D    256
#define C2D    128
#define C3D    512
#define BB     8
#define DD     64
#define NVALID 2080           // D*(D+1)/2 valid (h<=w) pixels
#define NCOLS  16640          // BB * NVALID
#define SCOLS  66560          // NS * NVALID
#define KDIM   4096           // C2D*NS
#define MASKROW 131072        // NS*DD*DD

// ws layout (bytes)
#define OFF_XB   0u           // bf16 [1024][256]        524288 B
#define OFF_W3B  524288u      // bf16 [512][4096]        4 MB
#define OFF_W2B  4718592u     // bf16 [128][512]         131072 B
#define OFF_CVEC 4849664u     // f32  [128]
#define OFF_PIX  4850176u     // int  [2080]
#define OFF_BM   8388608u     // bf16 [4096][16640]      136314880 B  (ws total ~145 MB)

__device__ __forceinline__ void gload_lds16(const void* g, void* l) {
    __builtin_amdgcn_global_load_lds(
        (const __attribute__((address_space(1))) void*)g,
        (__attribute__((address_space(3))) void*)l, 16, 0, 0);
}

// ---------------- conv1d(k=3,pad=1) + relu + cast -> xb[b*128+co][t] ---------
__global__ __launch_bounds__(256) void k_conv(const float* __restrict__ base,
                                              const float* __restrict__ w1,
                                              const float* __restrict__ b1,
                                              bf16* __restrict__ xb) {
    __shared__ float sb[C1D][10];
    int ttile = blockIdx.x;            // 0..31 (t-tile of 8)
    int b     = blockIdx.y;
    int t0    = ttile * 8;
    int tid   = threadIdx.x;
    for (int ci = tid; ci < C1D; ci += 256) {
        const float* src = base + (size_t)(b * C1D + ci) * TSCALE;
        #pragma unroll
        for (int j = 0; j < 10; j++) {
            int t = t0 - 1 + j;
            sb[ci][j] = (t >= 0 && t < TSCALE) ? src[t] : 0.f;
        }
    }
    __syncthreads();
    int co = tid & 127;
    int th = tid >> 7;                 // 0..1 (t half of 4)
    float bias = b1[co];
    float acc[4] = {bias, bias, bias, bias};
    const float* wp = w1 + (size_t)co * C1D * 3;
    int tl = th * 4;
    for (int ci = 0; ci < C1D; ci++) {
        float wa = wp[ci*3+0], wb = wp[ci*3+1], wc = wp[ci*3+2];
        #pragma unroll
        for (int j = 0; j < 4; j++)
            acc[j] += sb[ci][tl+j]*wa + sb[ci][tl+j+1]*wb + sb[ci][tl+j+2]*wc;
    }
    bf16* dst = xb + (size_t)(b * C2D + co) * TSCALE + t0 + tl;
    #pragma unroll
    for (int j = 0; j < 4; j++) {
        float v = acc[j] > 0.f ? acc[j] : 0.f;
        dst[j] = (bf16)v;
    }
}

// ---------------- cast w3 -> bf16 (layout [o][k=c*32+s] == input order) ------
__global__ __launch_bounds__(256) void k_cast_w3(const float* __restrict__ w3,
                                                 bf16* __restrict__ w3b) {
    int i = (blockIdx.x * 256 + threadIdx.x) * 4;
    float4 v = *(const float4*)(w3 + i);
    w3b[i+0] = (bf16)v.x; w3b[i+1] = (bf16)v.y;
    w3b[i+2] = (bf16)v.z; w3b[i+3] = (bf16)v.w;
}

// ---------------- misc: cvec, pix2hw table, w2 cast --------------------------
__global__ __launch_bounds__(256) void k_misc(const float* __restrict__ w2,
                                              const float* __restrict__ b2,
                                              const float* __restrict__ b3,
                                              bf16* __restrict__ w2b,
                                              float* __restrict__ cvec,
                                              int* __restrict__ pix2hw) {
    int tid = threadIdx.x;
    if (blockIdx.x == 0) {
        if (tid < C2D) {
            float s = b2[tid];
            for (int o = 0; o < C3D; o++) {
                float r = b3[o]; r = r > 0.f ? r : 0.f;
                s += w2[(size_t)tid * C3D + o] * r;
            }
            cvec[tid] = s > 0.f ? s : 0.f;
        }
        for (int pix = tid; pix < NVALID; pix += 256) {
            int h = 0, base = 0;
            while (pix >= base + (DD - h)) { base += DD - h; h++; }
            int w = h + (pix - base);
            pix2hw[pix] = h * DD + w;
        }
    } else {
        int i = ((blockIdx.x - 1) * 256 + tid) * 16;
        #pragma unroll
        for (int j = 0; j < 16; j++) w2b[i + j] = (bf16)w2[i + j];
    }
}

// ---------------- GEMM2: bm[k=(c,s)][n=(b,pix)] = x @ mask -------------------
// grid (1040 coltiles, 2 mhalves), 512 thr, tile 512x64, K=256
__global__ __launch_bounds__(512, 2) void k_gemm2(const bf16* __restrict__ xb,
                                                  const float* __restrict__ mask,
                                                  const int* __restrict__ pix2hw,
                                                  bf16* __restrict__ bm) {
    __shared__ __align__(16) bf16 As[512 * 32];
    __shared__ __align__(16) bf16 Bs[64 * 32];
    int tid = threadIdx.x, lane = tid & 63, wave = tid >> 6;
    int mhalf = blockIdx.y;
    int cg0 = blockIdx.x * 64;
    int m16 = lane & 15, q = lane >> 4, kq = lane & 3, ar = lane >> 2;

    // B staging: thread loads 4 (t,col) elems per k-step
    int tt = tid >> 4;                 // 0..31  t within chunk
    int cl = (tid & 15) * 4;           // col_local base
    int coloff[4];
    #pragma unroll
    for (int i = 0; i < 4; i++) {
        int cg = cg0 + cl + i;
        int s = cg / NVALID;
        int pix = cg - s * NVALID;
        coloff[i] = s * 4096 + pix2hw[pix];
    }
    f32x4 acc[4][4];
    #pragma unroll
    for (int i = 0; i < 4; i++)
        #pragma unroll
        for (int j = 0; j < 4; j++) acc[i][j] = (f32x4){0.f, 0.f, 0.f, 0.f};

    for (int kk = 0; kk < 8; kk++) {
        __syncthreads();
        #pragma unroll
        for (int j = 0; j < 4; j++) {
            int r0 = wave * 64 + j * 16;
            const bf16* g = xb + (size_t)(mhalf * 512 + r0 + ar) * TSCALE + kk * 32 + kq * 8;
            gload_lds16(g, &As[r0 * 32]);
        }
        {
            int t = kk * 32 + tt;
            const float* mrow = mask + (size_t)t * MASKROW;
            #pragma unroll
            for (int i = 0; i < 4; i++) {
                float v = mrow[coloff[i]];
                Bs[(cl + i) * 32 + tt] = (bf16)v;
            }
        }
        __syncthreads();
        bf16x8 af[4], bfr[4];
        #pragma unroll
        for (int i = 0; i < 4; i++)
            af[i] = *(const bf16x8*)&As[(wave * 64 + i * 16 + m16) * 32 + q * 8];
        #pragma unroll
        for (int j = 0; j < 4; j++)
            bfr[j] = *(const bf16x8*)&Bs[(j * 16 + m16) * 32 + q * 8];
        #pragma unroll
        for (int i = 0; i < 4; i++)
            #pragma unroll
            for (int j = 0; j < 4; j++)
                acc[i][j] = __builtin_amdgcn_mfma_f32_16x16x32_bf16(af[i], bfr[j], acc[i][j], 0, 0, 0);
    }
    int sarr[4], parr[4];
    #pragma unroll
    for (int j = 0; j < 4; j++) {
        int cg = cg0 + j * 16 + m16;
        int s = cg / NVALID;
        sarr[j] = s; parr[j] = cg - s * NVALID;
    }
    #pragma unroll
    for (int i = 0; i < 4; i++)
        #pragma unroll
        for (int r = 0; r < 4; r++) {
            int row = mhalf * 512 + wave * 64 + i * 16 + q * 4 + r;  // (b,c)
            int b = row >> 7, c = row & 127;
            #pragma unroll
            for (int j = 0; j < 4; j++)
                bm[(size_t)(c * 32 + sarr[j]) * NCOLS + b * NVALID + parr[j]] = (bf16)acc[i][j][r];
        }
}

// ---------------- GEMM3 (512x4096 @ 4096xN) + fused GEMM4 (128x512) ----------
// grid 260 coltiles of 64, 512 thr
__global__ __launch_bounds__(512, 2) void k_gemm34(const bf16* __restrict__ w3b,
                                                   const bf16* __restrict__ bm,
                                                   const float* __restrict__ b3,
                                                   const bf16* __restrict__ w2b,
                                                   const float* __restrict__ b2,
                                                   const int* __restrict__ pix2hw,
                                                   float* __restrict__ out) {
    __shared__ __align__(16) char lds[73728];
    bf16* As  = (bf16*)lds;             // [512][32]  (32 KB, K-loop)
    bf16* Bs  = (bf16*)(lds + 32768);   // [64][32]   (4 KB,  K-loop)
    bf16* x3s = (bf16*)lds;             // [64][512]  (64 KB, epilogue)
    bf16* A2s = (bf16*)(lds + 65536);   // [128][32]  (8 KB,  epilogue)

    int tid = threadIdx.x, lane = tid & 63, wave = tid >> 6;
    int n0 = blockIdx.x * 64;
    int m16 = lane & 15, q = lane >> 4, kq = lane & 3, ar = lane >> 2;
    int kk_b = tid >> 4;               // 0..31
    int n4   = (tid & 15) * 4;

    f32x4 acc[4][4];
    #pragma unroll
    for (int i = 0; i < 4; i++)
        #pragma unroll
        for (int j = 0; j < 4; j++) acc[i][j] = (f32x4){0.f, 0.f, 0.f, 0.f};

    for (int ks = 0; ks < 128; ks++) {
        int k0 = ks * 32;
        __syncthreads();
        #pragma unroll
        for (int j = 0; j < 4; j++) {
            int r0 = wave * 64 + j * 16;
            const bf16* g = w3b + (size_t)(r0 + ar) * KDIM + k0 + kq * 8;
            gload_lds16(g, &As[r0 * 32]);
        }
        {
            const bf16* src = bm + (size_t)(k0 + kk_b) * NCOLS + n0 + n4;
            union { uint2 u; bf16 h[4]; } tmp;
            tmp.u = *(const uint2*)src;
            #pragma unroll
            for (int i = 0; i < 4; i++) Bs[(n4 + i) * 32 + kk_b] = tmp.h[i];
        }
        __syncthreads();
        bf16x8 af[4], bfr[4];
        #pragma unroll
        for (int i = 0; i < 4; i++)
            af[i] = *(const bf16x8*)&As[(wave * 64 + i * 16 + m16) * 32 + q * 8];
        #pragma unroll
        for (int j = 0; j < 4; j++)
            bfr[j] = *(const bf16x8*)&Bs[(j * 16 + m16) * 32 + q * 8];
        #pragma unroll
        for (int i = 0; i < 4; i++)
            #pragma unroll
            for (int j = 0; j < 4; j++)
                acc[i][j] = __builtin_amdgcn_mfma_f32_16x16x32_bf16(af[i], bfr[j], acc[i][j], 0, 0, 0);
    }
    __syncthreads();
    // x3 = relu(acc + b3)  ->  x3s[n][o]  (bf16)
    #pragma unroll
    for (int i = 0; i < 4; i++)
        #pragma unroll
        for (int r = 0; r < 4; r++) {
            int o = wave * 64 + i * 16 + q * 4 + r;
            float bias = b3[o];
            #pragma unroll
            for (int j = 0; j < 4; j++) {
                int n = j * 16 + m16;
                float v = acc[i][j][r] + bias; v = v > 0.f ? v : 0.f;
                x3s[n * 512 + o] = (bf16)v;
            }
        }
    __syncthreads();
    // GEMM4: out2[o2][n] = relu(w2b @ x3 + b2), tile 128x64, wave -> 16 o2 rows
    f32x4 acc2[4];
    #pragma unroll
    for (int j = 0; j < 4; j++) acc2[j] = (f32x4){0.f, 0.f, 0.f, 0.f};
    for (int k2 = 0; k2 < 16; k2++) {
        __syncthreads();
        {
            int r0 = wave * 16;
            const bf16* g = w2b + (size_t)(r0 + ar) * C3D + k2 * 32 + kq * 8;
            gload_lds16(g, &A2s[r0 * 32]);
        }
        __syncthreads();
        bf16x8 a2 = *(const bf16x8*)&A2s[(wave * 16 + m16) * 32 + q * 8];
        #pragma unroll
        for (int j = 0; j < 4; j++) {
            bf16x8 bf2 = *(const bf16x8*)&x3s[(j * 16 + m16) * 512 + k2 * 32 + q * 8];
            acc2[j] = __builtin_amdgcn_mfma_f32_16x16x32_bf16(a2, bf2, acc2[j], 0, 0, 0);
        }
    }
    int barr[4], hwarr[4];
    #pragma unroll
    for (int j = 0; j < 4; j++) {
        int n = n0 + j * 16 + m16;
        int b = n / NVALID;
        barr[j] = b; hwarr[j] = pix2hw[n - b * NVALID];
    }
    #pragma unroll
    for (int j = 0; j < 4; j++)
        #pragma unroll
        for (int r = 0; r < 4; r++) {
            int o2 = wave * 16 + q * 4 + r;
            float v = acc2[j][r] + b2[o2]; v = v > 0.f ? v : 0.f;
            out[(size_t)barr[j] * 524288 + o2 * 4096 + hwarr[j]] = v;
        }
}

// ---------------- fill invalid (w < h) pixels with constant vector -----------
__global__ __launch_bounds__(256) void k_fill(const float* __restrict__ cvec,
                                              float* __restrict__ out) {
    int bo = blockIdx.x;               // b*128 + o2
    float v = cvec[bo & 127];
    float* dst = out + (size_t)bo * 4096;
    for (int hw = threadIdx.x; hw < 4096; hw += 256) {
        int h = hw >> 6, w = hw & 63;
        if (w < h) dst[hw] = v;
    }
}

extern "C" void kernel_launch(void* const* d_in, const int* in_sizes, int n_in,
                              void* d_out, int out_size, void* d_ws, size_t ws_size,
                              hipStream_t stream) {
    const float* base = (const float*)d_in[0];
    const float* w1   = (const float*)d_in[1];
    const float* b1   = (const float*)d_in[2];
    const float* w3   = (const float*)d_in[3];
    const float* b3   = (const float*)d_in[4];
    const float* w2   = (const float*)d_in[5];
    const float* b2   = (const float*)d_in[6];
    const float* mask = (const float*)d_in[7];
    float* out = (float*)d_out;
    char* ws = (char*)d_ws;
    bf16*  xb     = (bf16*)(ws + OFF_XB);
    bf16*  w3b    = (bf16*)(ws + OFF_W3B);
    bf16*  w2b    = (bf16*)(ws + OFF_W2B);
    float* cvec   = (float*)(ws + OFF_CVEC);
    int*   pix2hw = (int*)(ws + OFF_PIX);
    bf16*  bm     = (bf16*)(ws + OFF_BM);

    k_conv<<<dim3(32, 8), dim3(256), 0, stream>>>(base, w1, b1, xb);
    k_cast_w3<<<dim3(2048), dim3(256), 0, stream>>>(w3, w3b);
    k_misc<<<dim3(17), dim3(256), 0, stream>>>(w2, b2, b3, w2b, cvec, pix2hw);
    k_gemm2<<<dim3(1040, 2), dim3(512), 0, stream>>>(xb, mask, pix2hw, bm);
    k_gemm34<<<dim3(260), dim3(512), 0, stream>>>(w3b, bm, b3, w2b, b2, pix2hw, out);
    k_fill<<<dim3(1024), dim3(256), 0, stream>>>(cvec, out);
}

// Round 2
// 506.454 us; speedup vs baseline: 1.3141x; 1.3141x over previous
//
#include <hip/hip_runtime.h>
#include <stdint.h>

typedef __bf16 bf16;
typedef __bf16 bf16x8 __attribute__((ext_vector_type(8)));
typedef float  f32x4  __attribute__((ext_vector_type(4)));

#define NVALID 2080            // D*(D+1)/2 valid (h<=w) pixels
#define NCOLS  16640           // B*NVALID  (bm rows, n-dim)
#define KDIM   4096            // C2D*NS    (bm cols, k-dim)

// ws layout (bytes); total ~171 MiB
#define OFF_XB    0u           // bf16 [1024][256]
#define OFF_W3B   524288u      // bf16 [512][4096]
#define OFF_W2B   4718592u     // bf16 [128][512]
#define OFF_CVEC  4849664u     // f32  [128]
#define OFF_PIX   4850176u     // int  [2080]
#define OFF_MASKT 8388608u     // bf16 [2080][32][256] = 34 MB
#define OFF_X3    8388608u     // bf16 [16640][512] = 17 MB (aliases maskT; sequential)
#define OFF_BM    42991616u    // bf16 [16640][4096] = 136 MB

__device__ __forceinline__ void gload_lds16(const void* g, void* l) {
    __builtin_amdgcn_global_load_lds(
        (const __attribute__((address_space(1))) void*)g,
        (__attribute__((address_space(3))) void*)l, 16, 0, 0);
}

// Stage 16 rows x 32 k (bf16) into LDS with XOR swizzle: LDS slot (row, c)
// holds global chunk c ^ ((row>>1)&3). ldsbase+rbase*32 is wave-uniform.
__device__ __forceinline__ void stage16(const bf16* gbase, int stride, int rbase,
                                        int k0, bf16* ldsbase, int lane) {
    int row = rbase + (lane >> 2);
    int cg  = (lane & 3) ^ ((row >> 1) & 3);
    gload_lds16(gbase + (size_t)row * stride + k0 + cg * 8, ldsbase + rbase * 32);
}

// Read one MFMA A/B fragment (8 k-contig bf16) from a swizzled [rows][32] tile.
__device__ __forceinline__ bf16x8 fragld(const bf16* lds, int row, int q) {
    int c = q ^ ((row >> 1) & 3);
    return *(const bf16x8*)(lds + row * 32 + c * 8);
}

// ---------------- conv1d(k=3,pad=1) + relu + cast -> xb[b*128+co][t] ---------
__global__ __launch_bounds__(256) void k_conv(const float* __restrict__ base,
                                              const float* __restrict__ w1,
                                              const float* __restrict__ b1,
                                              bf16* __restrict__ xb) {
    __shared__ float sb[256][10];
    int ttile = blockIdx.x, b = blockIdx.y;
    int t0 = ttile * 8, tid = threadIdx.x;
    for (int ci = tid; ci < 256; ci += 256) {
        const float* src = base + (size_t)(b * 256 + ci) * 256;
        #pragma unroll
        for (int j = 0; j < 10; j++) {
            int t = t0 - 1 + j;
            sb[ci][j] = (t >= 0 && t < 256) ? src[t] : 0.f;
        }
    }
    __syncthreads();
    int co = tid & 127, th = tid >> 7;
    float bias = b1[co];
    float acc[4] = {bias, bias, bias, bias};
    const float* wp = w1 + (size_t)co * 768;
    int tl = th * 4;
    for (int ci = 0; ci < 256; ci++) {
        float wa = wp[ci*3+0], wb = wp[ci*3+1], wc = wp[ci*3+2];
        #pragma unroll
        for (int j = 0; j < 4; j++)
            acc[j] += sb[ci][tl+j]*wa + sb[ci][tl+j+1]*wb + sb[ci][tl+j+2]*wc;
    }
    bf16* dst = xb + (size_t)(b * 128 + co) * 256 + t0 + tl;
    #pragma unroll
    for (int j = 0; j < 4; j++) {
        float v = acc[j] > 0.f ? acc[j] : 0.f;
        dst[j] = (bf16)v;
    }
}

// ---------------- cast w3 -> bf16 [o][k=c*32+s] ------------------------------
__global__ __launch_bounds__(256) void k_cast_w3(const float* __restrict__ w3,
                                                 bf16* __restrict__ w3b) {
    int i = (blockIdx.x * 256 + threadIdx.x) * 4;
    float4 v = *(const float4*)(w3 + i);
    w3b[i+0] = (bf16)v.x; w3b[i+1] = (bf16)v.y;
    w3b[i+2] = (bf16)v.z; w3b[i+3] = (bf16)v.w;
}

// ---------------- misc: cvec, pix2hw table, w2 cast --------------------------
__global__ __launch_bounds__(256) void k_misc(const float* __restrict__ w2,
                                              const float* __restrict__ b2,
                                              const float* __restrict__ b3,
                                              bf16* __restrict__ w2b,
                                              float* __restrict__ cvec,
                                              int* __restrict__ pix2hw) {
    int tid = threadIdx.x;
    if (blockIdx.x == 0) {
        if (tid < 128) {
            float s = b2[tid];
            for (int o = 0; o < 512; o++) {
                float r = b3[o]; r = r > 0.f ? r : 0.f;
                s += w2[(size_t)tid * 512 + o] * r;
            }
            cvec[tid] = s > 0.f ? s : 0.f;
        }
        for (int pix = tid; pix < NVALID; pix += 256) {
            int h = 0, base = 0;
            while (pix >= base + (64 - h)) { base += 64 - h; h++; }
            int w = h + (pix - base);
            pix2hw[pix] = h * 64 + w;
        }
    } else {
        int i = ((blockIdx.x - 1) * 256 + tid) * 16;
        #pragma unroll
        for (int j = 0; j < 16; j++) w2b[i + j] = (bf16)w2[i + j];
    }
}

// ---------------- maskT[pix][s][t] bf16: gather valid cols + transpose -------
// grid (33 pixtiles of 64, 64 combo-groups), 256 thr
__global__ __launch_bounds__(256) void k_maskT(const float* __restrict__ mask,
                                               const int* __restrict__ pix2hw,
                                               bf16* __restrict__ maskT) {
    int tid = threadIdx.x;
    int pix = blockIdx.x * 64 + (tid & 63);
    if (pix >= NVALID) return;
    int combo = blockIdx.y * 4 + (tid >> 6);
    int s = combo >> 3, tc = combo & 7;
    int colo = s * 4096 + pix2hw[pix];
    bf16x8 v[4];
    #pragma unroll
    for (int i = 0; i < 32; i++) {
        float f = mask[(size_t)(tc * 32 + i) * 131072 + colo];
        v[i >> 3][i & 7] = (bf16)f;
    }
    bf16* dst = maskT + (size_t)pix * 8192 + s * 256 + tc * 32;
    #pragma unroll
    for (int k = 0; k < 4; k++) *(bf16x8*)(dst + k * 8) = v[k];
}

// ---------------- GEMM2: bm[n=(b,p)][k=(c,s)] = maskT @ xb_b^T ---------------
// A = maskT rows ps=(p,s) [128], B = xb rows c [128], K = t (256), per-b batch.
// grid (520 ps-tiles, 8 b), 256 thr (4 waves, 2x2 of 64x64)
__global__ __launch_bounds__(256, 4) void k_gemm2(const bf16* __restrict__ maskT,
                                                  const bf16* __restrict__ xb,
                                                  bf16* __restrict__ bm) {
    __shared__ __align__(16) char lds[33024];
    bf16* As0 = (bf16*)lds;              // [2][128][32]
    bf16* Bs0 = (bf16*)(lds + 16384);    // [2][128][32]
    bf16* T2  = (bf16*)lds;              // [4][4104] epilogue transpose

    int tid = threadIdx.x, lane = tid & 63, wave = tid >> 6;
    int m16 = lane & 15, q = lane >> 4;
    int wm = wave >> 1, wn = wave & 1;
    int b = blockIdx.y, ps0 = blockIdx.x * 128;
    const bf16* Ag = maskT + (size_t)ps0 * 256;
    const bf16* Bg = xb + (size_t)b * 32768;

    f32x4 acc[4][4];
    #pragma unroll
    for (int i = 0; i < 4; i++)
        #pragma unroll
        for (int j = 0; j < 4; j++) acc[i][j] = (f32x4){0.f, 0.f, 0.f, 0.f};

    stage16(Ag, 256, wave * 32,      0, As0, lane);
    stage16(Ag, 256, wave * 32 + 16, 0, As0, lane);
    stage16(Bg, 256, wave * 32,      0, Bs0, lane);
    stage16(Bg, 256, wave * 32 + 16, 0, Bs0, lane);

    for (int ks = 0; ks < 8; ks++) {
        __syncthreads();
        if (ks < 7) {
            int k0 = (ks + 1) * 32, o = ((ks + 1) & 1) * 4096;
            stage16(Ag, 256, wave * 32,      k0, As0 + o, lane);
            stage16(Ag, 256, wave * 32 + 16, k0, As0 + o, lane);
            stage16(Bg, 256, wave * 32,      k0, Bs0 + o, lane);
            stage16(Bg, 256, wave * 32 + 16, k0, Bs0 + o, lane);
        }
        const bf16* Ac = As0 + (ks & 1) * 4096;
        const bf16* Bc = Bs0 + (ks & 1) * 4096;
        bf16x8 af[4], bfv[4];
        #pragma unroll
        for (int i = 0; i < 4; i++) af[i]  = fragld(Ac, wm * 64 + i * 16 + m16, q);
        #pragma unroll
        for (int j = 0; j < 4; j++) bfv[j] = fragld(Bc, wn * 64 + j * 16 + m16, q);
        #pragma unroll
        for (int i = 0; i < 4; i++)
            #pragma unroll
            for (int j = 0; j < 4; j++)
                acc[i][j] = __builtin_amdgcn_mfma_f32_16x16x32_bf16(af[i], bfv[j], acc[i][j], 0, 0, 0);
    }
    __syncthreads();
    // transpose to 4 complete bm rows: T2[p_l][c*32 + (s ^ 8*((c>>2)&3))]
    #pragma unroll
    for (int i = 0; i < 4; i++)
        #pragma unroll
        for (int r = 0; r < 4; r++) {
            int m = wm * 64 + i * 16 + q * 4 + r;
            int p_l = m >> 5, s = m & 31;
            #pragma unroll
            for (int j = 0; j < 4; j++) {
                int c = wn * 64 + j * 16 + m16;
                int K = (c >> 2) & 3;
                T2[p_l * 4104 + c * 32 + (s ^ (K << 3))] = (bf16)acc[i][j][r];
            }
        }
    __syncthreads();
    int n_l = tid >> 6, seg = tid & 63;
    bf16* dst = bm + ((size_t)b * NVALID + blockIdx.x * 4 + n_l) * (size_t)KDIM;
    #pragma unroll
    for (int m2 = 0; m2 < 8; m2++) {
        int cblk = seg * 2 + (m2 >> 2), sblk = m2 & 3;
        int K = (cblk >> 2) & 3;
        *(bf16x8*)(dst + cblk * 32 + sblk * 8) =
            *(const bf16x8*)(T2 + n_l * 4104 + cblk * 32 + ((sblk ^ K) << 3));
    }
}

// ---------------- GEMM3: x3[n][o] = relu(w3b @ bm^T + b3), K=4096 ------------
// grid (130 n-tiles, 4 o-tiles), 256 thr (4 waves, 2x2 of 64x64)
__global__ __launch_bounds__(256, 2) void k_gemm3(const bf16* __restrict__ w3b,
                                                  const bf16* __restrict__ bm,
                                                  const float* __restrict__ b3,
                                                  bf16* __restrict__ x3) {
    __shared__ __align__(16) char lds[34816];
    bf16* As0 = (bf16*)lds;              // [2][128][32] (o-rows)
    bf16* Bs0 = (bf16*)(lds + 16384);    // [2][128][32] (n-rows)
    bf16* T2  = (bf16*)lds;              // [128][136] epilogue

    int tid = threadIdx.x, lane = tid & 63, wave = tid >> 6;
    int m16 = lane & 15, q = lane >> 4;
    int wm = wave >> 1, wn = wave & 1;
    int n0 = blockIdx.x * 128, o0 = blockIdx.y * 128;
    const bf16* Ag = w3b + (size_t)o0 * KDIM;
    const bf16* Bg = bm + (size_t)n0 * KDIM;

    f32x4 acc[4][4];
    #pragma unroll
    for (int i = 0; i < 4; i++)
        #pragma unroll
        for (int j = 0; j < 4; j++) acc[i][j] = (f32x4){0.f, 0.f, 0.f, 0.f};

    stage16(Ag, KDIM, wave * 32,      0, As0, lane);
    stage16(Ag, KDIM, wave * 32 + 16, 0, As0, lane);
    stage16(Bg, KDIM, wave * 32,      0, Bs0, lane);
    stage16(Bg, KDIM, wave * 32 + 16, 0, Bs0, lane);

    for (int ks = 0; ks < 128; ks++) {
        __syncthreads();
        if (ks < 127) {
            int k0 = (ks + 1) * 32, o = ((ks + 1) & 1) * 4096;
            stage16(Ag, KDIM, wave * 32,      k0, As0 + o, lane);
            stage16(Ag, KDIM, wave * 32 + 16, k0, As0 + o, lane);
            stage16(Bg, KDIM, wave * 32,      k0, Bs0 + o, lane);
            stage16(Bg, KDIM, wave * 32 + 16, k0, Bs0 + o, lane);
        }
        const bf16* Ac = As0 + (ks & 1) * 4096;
        const bf16* Bc = Bs0 + (ks & 1) * 4096;
        bf16x8 af[4], bfv[4];
        #pragma unroll
        for (int i = 0; i < 4; i++) af[i]  = fragld(Ac, wm * 64 + i * 16 + m16, q);
        #pragma unroll
        for (int j = 0; j < 4; j++) bfv[j] = fragld(Bc, wn * 64 + j * 16 + m16, q);
        #pragma unroll
        for (int i = 0; i < 4; i++)
            #pragma unroll
            for (int j = 0; j < 4; j++)
                acc[i][j] = __builtin_amdgcn_mfma_f32_16x16x32_bf16(af[i], bfv[j], acc[i][j], 0, 0, 0);
    }
    __syncthreads();
    #pragma unroll
    for (int i = 0; i < 4; i++)
        #pragma unroll
        for (int r = 0; r < 4; r++) {
            int o_l = wm * 64 + i * 16 + q * 4 + r;
            float bias = b3[o0 + o_l];
            #pragma unroll
            for (int j = 0; j < 4; j++) {
                int n_l = wn * 64 + j * 16 + m16;
                float v = acc[i][j][r] + bias; v = v > 0.f ? v : 0.f;
                T2[n_l * 136 + o_l] = (bf16)v;
            }
        }
    __syncthreads();
    {
        int n_l = tid >> 1, half = (tid & 1) * 64;
        bf16* dst = x3 + (size_t)(n0 + n_l) * 512 + o0 + half;
        const bf16* src = T2 + n_l * 136 + half;
        #pragma unroll
        for (int m = 0; m < 8; m++)
            *(bf16x8*)(dst + m * 8) = *(const bf16x8*)(src + m * 8);
    }
}

// ---------------- GEMM4: out = relu(w2b @ x3^T + b2), K=512 ------------------
// grid (260 n-tiles), 256 thr (4 waves, wave-tile 32x64)
__global__ __launch_bounds__(256, 2) void k_gemm4(const bf16* __restrict__ w2b,
                                                  const bf16* __restrict__ x3,
                                                  const float* __restrict__ b2,
                                                  const int* __restrict__ pix2hw,
                                                  float* __restrict__ out) {
    __shared__ __align__(16) char lds[24576];
    bf16* As0 = (bf16*)lds;              // [2][128][32] (o2-rows)
    bf16* Bs0 = (bf16*)(lds + 16384);    // [2][64][32]  (n-rows)

    int tid = threadIdx.x, lane = tid & 63, wave = tid >> 6;
    int m16 = lane & 15, q = lane >> 4;
    int n0 = blockIdx.x * 64;
    const bf16* Ag = w2b;
    const bf16* Bg = x3 + (size_t)n0 * 512;

    f32x4 acc[2][4];
    #pragma unroll
    for (int i = 0; i < 2; i++)
        #pragma unroll
        for (int j = 0; j < 4; j++) acc[i][j] = (f32x4){0.f, 0.f, 0.f, 0.f};

    stage16(Ag, 512, wave * 32,      0, As0, lane);
    stage16(Ag, 512, wave * 32 + 16, 0, As0, lane);
    stage16(Bg, 512, wave * 16,      0, Bs0, lane);

    for (int ks = 0; ks < 16; ks++) {
        __syncthreads();
        if (ks < 15) {
            int k0 = (ks + 1) * 32, oA = ((ks + 1) & 1) * 4096, oB = ((ks + 1) & 1) * 2048;
            stage16(Ag, 512, wave * 32,      k0, As0 + oA, lane);
            stage16(Ag, 512, wave * 32 + 16, k0, As0 + oA, lane);
            stage16(Bg, 512, wave * 16,      k0, Bs0 + oB, lane);
        }
        const bf16* Ac = As0 + (ks & 1) * 4096;
        const bf16* Bc = Bs0 + (ks & 1) * 2048;
        bf16x8 af[2], bfv[4];
        #pragma unroll
        for (int i = 0; i < 2; i++) af[i]  = fragld(Ac, wave * 32 + i * 16 + m16, q);
        #pragma unroll
        for (int j = 0; j < 4; j++) bfv[j] = fragld(Bc, j * 16 + m16, q);
        #pragma unroll
        for (int i = 0; i < 2; i++)
            #pragma unroll
            for (int j = 0; j < 4; j++)
                acc[i][j] = __builtin_amdgcn_mfma_f32_16x16x32_bf16(af[i], bfv[j], acc[i][j], 0, 0, 0);
    }
    int barr[4], hwarr[4];
    #pragma unroll
    for (int j = 0; j < 4; j++) {
        int n = n0 + j * 16 + m16;
        int bb = n / NVALID;
        barr[j] = bb; hwarr[j] = pix2hw[n - bb * NVALID];
    }
    #pragma unroll
    for (int i = 0; i < 2; i++)
        #pragma unroll
        for (int r = 0; r < 4; r++) {
            int o2 = wave * 32 + i * 16 + q * 4 + r;
            float bias = b2[o2];
            #pragma unroll
            for (int j = 0; j < 4; j++) {
                float v = acc[i][j][r] + bias; v = v > 0.f ? v : 0.f;
                out[(size_t)barr[j] * 524288 + o2 * 4096 + hwarr[j]] = v;
            }
        }
}

// ---------------- fill invalid (w < h) pixels with constant vector -----------
__global__ __launch_bounds__(256) void k_fill(const float* __restrict__ cvec,
                                              float* __restrict__ out) {
    int bo = blockIdx.x;
    float v = cvec[bo & 127];
    float* dst = out + (size_t)bo * 4096;
    for (int hw = threadIdx.x; hw < 4096; hw += 256) {
        int h = hw >> 6, w = hw & 63;
        if (w < h) dst[hw] = v;
    }
}

extern "C" void kernel_launch(void* const* d_in, const int* in_sizes, int n_in,
                              void* d_out, int out_size, void* d_ws, size_t ws_size,
                              hipStream_t stream) {
    const float* base = (const float*)d_in[0];
    const float* w1   = (const float*)d_in[1];
    const float* b1   = (const float*)d_in[2];
    const float* w3   = (const float*)d_in[3];
    const float* b3   = (const float*)d_in[4];
    const float* w2   = (const float*)d_in[5];
    const float* b2   = (const float*)d_in[6];
    const float* mask = (const float*)d_in[7];
    float* out = (float*)d_out;
    char* ws = (char*)d_ws;
    bf16*  xb     = (bf16*)(ws + OFF_XB);
    bf16*  w3b    = (bf16*)(ws + OFF_W3B);
    bf16*  w2b    = (bf16*)(ws + OFF_W2B);
    float* cvec   = (float*)(ws + OFF_CVEC);
    int*   pix2hw = (int*)(ws + OFF_PIX);
    bf16*  maskT  = (bf16*)(ws + OFF_MASKT);
    bf16*  x3     = (bf16*)(ws + OFF_X3);
    bf16*  bm     = (bf16*)(ws + OFF_BM);

    k_conv<<<dim3(32, 8), dim3(256), 0, stream>>>(base, w1, b1, xb);
    k_cast_w3<<<dim3(2048), dim3(256), 0, stream>>>(w3, w3b);
    k_misc<<<dim3(17), dim3(256), 0, stream>>>(w2, b2, b3, w2b, cvec, pix2hw);
    k_maskT<<<dim3(33, 64), dim3(256), 0, stream>>>(mask, pix2hw, maskT);
    k_gemm2<<<dim3(520, 8), dim3(256), 0, stream>>>(maskT, xb, bm);
    k_gemm3<<<dim3(130, 4), dim3(256), 0, stream>>>(w3b, bm, b3, x3);
    k_gemm4<<<dim3(260), dim3(256), 0, stream>>>(w2b, x3, b2, pix2hw, out);
    k_fill<<<dim3(1024), dim3(256), 0, stream>>>(cvec, out);
}

// Round 3
// 455.165 us; speedup vs baseline: 1.4622x; 1.1127x over previous
//
#include <hip/hip_runtime.h>
#include <stdint.h>

typedef __bf16 bf16;
typedef __bf16 bf16x8 __attribute__((ext_vector_type(8)));
typedef float  f32x4  __attribute__((ext_vector_type(4)));

#define NVALID 2080            // D*(D+1)/2 valid (h<=w) pixels
#define NCOLS  16640           // B*NVALID  (bm rows, n-dim)
#define KDIM   4096            // C2D*NS    (bm cols, k-dim)

// ws layout (bytes); total ~171 MiB
#define OFF_XB    0u           // bf16 [1024][256]
#define OFF_W3B   524288u      // bf16 [512][4096]
#define OFF_W2B   4718592u     // bf16 [128][512]
#define OFF_CVEC  4849664u     // f32  [128]
#define OFF_PIX   4850176u     // int  [2080]
#define OFF_MASKT 8388608u     // bf16 [2080][32][256] = 34 MB
#define OFF_X3    8388608u     // bf16 [16640][512] = 17 MB (aliases maskT; sequential)
#define OFF_BM    42991616u    // bf16 [16640][4096] = 136 MB

__device__ __forceinline__ void gload_lds16(const void* g, void* l) {
    __builtin_amdgcn_global_load_lds(
        (const __attribute__((address_space(1))) void*)g,
        (__attribute__((address_space(3))) void*)l, 16, 0, 0);
}

// Stage 16 rows x 32 k (bf16) into LDS with XOR swizzle: LDS slot (row, c)
// holds global chunk c ^ ((row>>1)&3). ldsbase+rbase*32 is wave-uniform.
__device__ __forceinline__ void stage16(const bf16* gbase, int stride, int rbase,
                                        int k0, bf16* ldsbase, int lane) {
    int row = rbase + (lane >> 2);
    int cg  = (lane & 3) ^ ((row >> 1) & 3);
    gload_lds16(gbase + (size_t)row * stride + k0 + cg * 8, ldsbase + rbase * 32);
}

// Read one MFMA A/B fragment (8 k-contig bf16) from a swizzled [rows][32] tile.
__device__ __forceinline__ bf16x8 fragld(const bf16* lds, int row, int q) {
    int c = q ^ ((row >> 1) & 3);
    return *(const bf16x8*)(lds + row * 32 + c * 8);
}

// ---------------- conv1d(k=3,pad=1) + relu + cast -> xb[b*128+co][t] ---------
__global__ __launch_bounds__(256) void k_conv(const float* __restrict__ base,
                                              const float* __restrict__ w1,
                                              const float* __restrict__ b1,
                                              bf16* __restrict__ xb) {
    __shared__ float sb[256][10];
    int ttile = blockIdx.x, b = blockIdx.y;
    int t0 = ttile * 8, tid = threadIdx.x;
    for (int ci = tid; ci < 256; ci += 256) {
        const float* src = base + (size_t)(b * 256 + ci) * 256;
        #pragma unroll
        for (int j = 0; j < 10; j++) {
            int t = t0 - 1 + j;
            sb[ci][j] = (t >= 0 && t < 256) ? src[t] : 0.f;
        }
    }
    __syncthreads();
    int co = tid & 127, th = tid >> 7;
    float bias = b1[co];
    float acc[4] = {bias, bias, bias, bias};
    const float* wp = w1 + (size_t)co * 768;
    int tl = th * 4;
    for (int ci = 0; ci < 256; ci++) {
        float wa = wp[ci*3+0], wb = wp[ci*3+1], wc = wp[ci*3+2];
        #pragma unroll
        for (int j = 0; j < 4; j++)
            acc[j] += sb[ci][tl+j]*wa + sb[ci][tl+j+1]*wb + sb[ci][tl+j+2]*wc;
    }
    bf16* dst = xb + (size_t)(b * 128 + co) * 256 + t0 + tl;
    #pragma unroll
    for (int j = 0; j < 4; j++) {
        float v = acc[j] > 0.f ? acc[j] : 0.f;
        dst[j] = (bf16)v;
    }
}

// ---------------- misc: cvec, pix2hw, w2 cast, w3 cast (merged) --------------
// grid 2065: block 0 = cvec+pix2hw, 1..16 = w2 cast, 17..2064 = w3 cast
__global__ __launch_bounds__(256) void k_misc(const float* __restrict__ w2,
                                              const float* __restrict__ b2,
                                              const float* __restrict__ b3,
                                              const float* __restrict__ w3,
                                              bf16* __restrict__ w2b,
                                              bf16* __restrict__ w3b,
                                              float* __restrict__ cvec,
                                              int* __restrict__ pix2hw) {
    int tid = threadIdx.x;
    if (blockIdx.x == 0) {
        if (tid < 128) {
            float s = b2[tid];
            for (int o = 0; o < 512; o++) {
                float r = b3[o]; r = r > 0.f ? r : 0.f;
                s += w2[(size_t)tid * 512 + o] * r;
            }
            cvec[tid] = s > 0.f ? s : 0.f;
        }
        for (int pix = tid; pix < NVALID; pix += 256) {
            int h = 0, base = 0;
            while (pix >= base + (64 - h)) { base += 64 - h; h++; }
            int w = h + (pix - base);
            pix2hw[pix] = h * 64 + w;
        }
    } else if (blockIdx.x <= 16) {
        int i = ((blockIdx.x - 1) * 256 + tid) * 16;
        #pragma unroll
        for (int j = 0; j < 16; j++) w2b[i + j] = (bf16)w2[i + j];
    } else {
        int i = ((blockIdx.x - 17) * 256 + tid) * 4;
        float4 v = *(const float4*)(w3 + i);
        w3b[i+0] = (bf16)v.x; w3b[i+1] = (bf16)v.y;
        w3b[i+2] = (bf16)v.z; w3b[i+3] = (bf16)v.w;
    }
}

// ---------------- maskT[pix][s][t] bf16: gather valid cols + transpose -------
// grid (33 pixtiles of 64, 64 combo-groups), 256 thr
__global__ __launch_bounds__(256) void k_maskT(const float* __restrict__ mask,
                                               const int* __restrict__ pix2hw,
                                               bf16* __restrict__ maskT) {
    int tid = threadIdx.x;
    int pix = blockIdx.x * 64 + (tid & 63);
    if (pix >= NVALID) return;
    int combo = blockIdx.y * 4 + (tid >> 6);
    int s = combo >> 3, tc = combo & 7;
    int colo = s * 4096 + pix2hw[pix];
    bf16x8 v[4];
    #pragma unroll
    for (int i = 0; i < 32; i++) {
        float f = mask[(size_t)(tc * 32 + i) * 131072 + colo];
        v[i >> 3][i & 7] = (bf16)f;
    }
    bf16* dst = maskT + (size_t)pix * 8192 + s * 256 + tc * 32;
    #pragma unroll
    for (int k = 0; k < 4; k++) *(bf16x8*)(dst + k * 8) = v[k];
}

// ---------------- GEMM2: bm[n=(b,p)][k=(c,s)] = maskT @ xb_b^T ---------------
// 1-D grid 4160, groups of 64: xcd=id&7, b=(id>>3)&7, ps=(id>>6)*8+xcd.
// The 8 b-blocks sharing a maskT ps-tile land on one XCD -> L2 reuse.
__global__ __launch_bounds__(256, 4) void k_gemm2(const bf16* __restrict__ maskT,
                                                  const bf16* __restrict__ xb,
                                                  bf16* __restrict__ bm) {
    __shared__ __align__(16) char lds[33024];
    bf16* As0 = (bf16*)lds;              // [2][128][32]
    bf16* Bs0 = (bf16*)(lds + 16384);    // [2][128][32]
    bf16* T2  = (bf16*)lds;              // [4][4104] epilogue transpose

    int tid = threadIdx.x, lane = tid & 63, wave = tid >> 6;
    int m16 = lane & 15, q = lane >> 4;
    int wm = wave >> 1, wn = wave & 1;
    int id = blockIdx.x;
    int b = (id >> 3) & 7;
    int pst = (id >> 6) * 8 + (id & 7);
    int ps0 = pst * 128;
    const bf16* Ag = maskT + (size_t)ps0 * 256;
    const bf16* Bg = xb + (size_t)b * 32768;

    f32x4 acc[4][4];
    #pragma unroll
    for (int i = 0; i < 4; i++)
        #pragma unroll
        for (int j = 0; j < 4; j++) acc[i][j] = (f32x4){0.f, 0.f, 0.f, 0.f};

    stage16(Ag, 256, wave * 32,      0, As0, lane);
    stage16(Ag, 256, wave * 32 + 16, 0, As0, lane);
    stage16(Bg, 256, wave * 32,      0, Bs0, lane);
    stage16(Bg, 256, wave * 32 + 16, 0, Bs0, lane);

    for (int ks = 0; ks < 8; ks++) {
        __syncthreads();
        if (ks < 7) {
            int k0 = (ks + 1) * 32, o = ((ks + 1) & 1) * 4096;
            stage16(Ag, 256, wave * 32,      k0, As0 + o, lane);
            stage16(Ag, 256, wave * 32 + 16, k0, As0 + o, lane);
            stage16(Bg, 256, wave * 32,      k0, Bs0 + o, lane);
            stage16(Bg, 256, wave * 32 + 16, k0, Bs0 + o, lane);
        }
        const bf16* Ac = As0 + (ks & 1) * 4096;
        const bf16* Bc = Bs0 + (ks & 1) * 4096;
        bf16x8 af[4], bfv[4];
        #pragma unroll
        for (int i = 0; i < 4; i++) af[i]  = fragld(Ac, wm * 64 + i * 16 + m16, q);
        #pragma unroll
        for (int j = 0; j < 4; j++) bfv[j] = fragld(Bc, wn * 64 + j * 16 + m16, q);
        #pragma unroll
        for (int i = 0; i < 4; i++)
            #pragma unroll
            for (int j = 0; j < 4; j++)
                acc[i][j] = __builtin_amdgcn_mfma_f32_16x16x32_bf16(af[i], bfv[j], acc[i][j], 0, 0, 0);
    }
    __syncthreads();
    // transpose to 4 complete bm rows: T2[p_l][c*32 + (s ^ 8*((c>>2)&3))]
    #pragma unroll
    for (int i = 0; i < 4; i++)
        #pragma unroll
        for (int r = 0; r < 4; r++) {
            int m = wm * 64 + i * 16 + q * 4 + r;
            int p_l = m >> 5, s = m & 31;
            #pragma unroll
            for (int j = 0; j < 4; j++) {
                int c = wn * 64 + j * 16 + m16;
                int K = (c >> 2) & 3;
                T2[p_l * 4104 + c * 32 + (s ^ (K << 3))] = (bf16)acc[i][j][r];
            }
        }
    __syncthreads();
    int n_l = tid >> 6, seg = tid & 63;
    bf16* dst = bm + ((size_t)b * NVALID + pst * 4 + n_l) * (size_t)KDIM;
    #pragma unroll
    for (int m2 = 0; m2 < 8; m2++) {
        int cblk = seg * 2 + (m2 >> 2), sblk = m2 & 3;
        int K = (cblk >> 2) & 3;
        *(bf16x8*)(dst + cblk * 32 + sblk * 8) =
            *(const bf16x8*)(T2 + n_l * 4104 + cblk * 32 + ((sblk ^ K) << 3));
    }
}

// ---------------- GEMM3: x3[n][o] = relu(w3b @ bm^T + b3), K=4096 ------------
// 1-D grid 520. ids [0,512): xcd=id&7, o=(id>>3)&3, n=(id>>5)*8+xcd;
// ids [512,520): r=id-512, n=128+(r&1), o=r>>1.
// The 4 o-blocks of one n-tile share an XCD -> bm slab (1 MB) hits L2.
__global__ __launch_bounds__(256, 2) void k_gemm3(const bf16* __restrict__ w3b,
                                                  const bf16* __restrict__ bm,
                                                  const float* __restrict__ b3,
                                                  bf16* __restrict__ x3) {
    __shared__ __align__(16) char lds[34816];
    bf16* As0 = (bf16*)lds;              // [2][128][32] (o-rows)
    bf16* Bs0 = (bf16*)(lds + 16384);    // [2][128][32] (n-rows)
    bf16* T2  = (bf16*)lds;              // [128][136] epilogue

    int tid = threadIdx.x, lane = tid & 63, wave = tid >> 6;
    int m16 = lane & 15, q = lane >> 4;
    int wm = wave >> 1, wn = wave & 1;
    int id = blockIdx.x, nt, ot;
    if (id >= 512) { int r = id - 512; nt = 128 + (r & 1); ot = r >> 1; }
    else           { nt = (id >> 5) * 8 + (id & 7); ot = (id >> 3) & 3; }
    int n0 = nt * 128, o0 = ot * 128;
    const bf16* Ag = w3b + (size_t)o0 * KDIM;
    const bf16* Bg = bm + (size_t)n0 * KDIM;

    f32x4 acc[4][4];
    #pragma unroll
    for (int i = 0; i < 4; i++)
        #pragma unroll
        for (int j = 0; j < 4; j++) acc[i][j] = (f32x4){0.f, 0.f, 0.f, 0.f};

    stage16(Ag, KDIM, wave * 32,      0, As0, lane);
    stage16(Ag, KDIM, wave * 32 + 16, 0, As0, lane);
    stage16(Bg, KDIM, wave * 32,      0, Bs0, lane);
    stage16(Bg, KDIM, wave * 32 + 16, 0, Bs0, lane);

    for (int ks = 0; ks < 128; ks++) {
        __syncthreads();
        if (ks < 127) {
            int k0 = (ks + 1) * 32, o = ((ks + 1) & 1) * 4096;
            stage16(Ag, KDIM, wave * 32,      k0, As0 + o, lane);
            stage16(Ag, KDIM, wave * 32 + 16, k0, As0 + o, lane);
            stage16(Bg, KDIM, wave * 32,      k0, Bs0 + o, lane);
            stage16(Bg, KDIM, wave * 32 + 16, k0, Bs0 + o, lane);
        }
        const bf16* Ac = As0 + (ks & 1) * 4096;
        const bf16* Bc = Bs0 + (ks & 1) * 4096;
        bf16x8 af[4], bfv[4];
        #pragma unroll
        for (int i = 0; i < 4; i++) af[i]  = fragld(Ac, wm * 64 + i * 16 + m16, q);
        #pragma unroll
        for (int j = 0; j < 4; j++) bfv[j] = fragld(Bc, wn * 64 + j * 16 + m16, q);
        #pragma unroll
        for (int i = 0; i < 4; i++)
            #pragma unroll
            for (int j = 0; j < 4; j++)
                acc[i][j] = __builtin_amdgcn_mfma_f32_16x16x32_bf16(af[i], bfv[j], acc[i][j], 0, 0, 0);
    }
    __syncthreads();
    #pragma unroll
    for (int i = 0; i < 4; i++)
        #pragma unroll
        for (int r = 0; r < 4; r++) {
            int o_l = wm * 64 + i * 16 + q * 4 + r;
            float bias = b3[o0 + o_l];
            #pragma unroll
            for (int j = 0; j < 4; j++) {
                int n_l = wn * 64 + j * 16 + m16;
                float v = acc[i][j][r] + bias; v = v > 0.f ? v : 0.f;
                T2[n_l * 136 + o_l] = (bf16)v;
            }
        }
    __syncthreads();
    {
        int n_l = tid >> 1, half = (tid & 1) * 64;
        bf16* dst = x3 + (size_t)(n0 + n_l) * 512 + o0 + half;
        const bf16* src = T2 + n_l * 136 + half;
        #pragma unroll
        for (int m = 0; m < 8; m++)
            *(bf16x8*)(dst + m * 8) = *(const bf16x8*)(src + m * 8);
    }
}

// ---------------- GEMM4: out = relu(w2b @ x3^T + b2), K=512 ------------------
// grid (260 n-tiles), 256 thr (4 waves, wave-tile 32x64)
__global__ __launch_bounds__(256, 2) void k_gemm4(const bf16* __restrict__ w2b,
                                                  const bf16* __restrict__ x3,
                                                  const float* __restrict__ b2,
                                                  const int* __restrict__ pix2hw,
                                                  float* __restrict__ out) {
    __shared__ __align__(16) char lds[24576];
    bf16* As0 = (bf16*)lds;              // [2][128][32] (o2-rows)
    bf16* Bs0 = (bf16*)(lds + 16384);    // [2][64][32]  (n-rows)

    int tid = threadIdx.x, lane = tid & 63, wave = tid >> 6;
    int m16 = lane & 15, q = lane >> 4;
    int n0 = blockIdx.x * 64;
    const bf16* Ag = w2b;
    const bf16* Bg = x3 + (size_t)n0 * 512;

    f32x4 acc[2][4];
    #pragma unroll
    for (int i = 0; i < 2; i++)
        #pragma unroll
        for (int j = 0; j < 4; j++) acc[i][j] = (f32x4){0.f, 0.f, 0.f, 0.f};

    stage16(Ag, 512, wave * 32,      0, As0, lane);
    stage16(Ag, 512, wave * 32 + 16, 0, As0, lane);
    stage16(Bg, 512, wave * 16,      0, Bs0, lane);

    for (int ks = 0; ks < 16; ks++) {
        __syncthreads();
        if (ks < 15) {
            int k0 = (ks + 1) * 32, oA = ((ks + 1) & 1) * 4096, oB = ((ks + 1) & 1) * 2048;
            stage16(Ag, 512, wave * 32,      k0, As0 + oA, lane);
            stage16(Ag, 512, wave * 32 + 16, k0, As0 + oA, lane);
            stage16(Bg, 512, wave * 16,      k0, Bs0 + oB, lane);
        }
        const bf16* Ac = As0 + (ks & 1) * 4096;
        const bf16* Bc = Bs0 + (ks & 1) * 2048;
        bf16x8 af[2], bfv[4];
        #pragma unroll
        for (int i = 0; i < 2; i++) af[i]  = fragld(Ac, wave * 32 + i * 16 + m16, q);
        #pragma unroll
        for (int j = 0; j < 4; j++) bfv[j] = fragld(Bc, j * 16 + m16, q);
        #pragma unroll
        for (int i = 0; i < 2; i++)
            #pragma unroll
            for (int j = 0; j < 4; j++)
                acc[i][j] = __builtin_amdgcn_mfma_f32_16x16x32_bf16(af[i], bfv[j], acc[i][j], 0, 0, 0);
    }
    int barr[4], hwarr[4];
    #pragma unroll
    for (int j = 0; j < 4; j++) {
        int n = n0 + j * 16 + m16;
        int bb = n / NVALID;
        barr[j] = bb; hwarr[j] = pix2hw[n - bb * NVALID];
    }
    #pragma unroll
    for (int i = 0; i < 2; i++)
        #pragma unroll
        for (int r = 0; r < 4; r++) {
            int o2 = wave * 32 + i * 16 + q * 4 + r;
            float bias = b2[o2];
            #pragma unroll
            for (int j = 0; j < 4; j++) {
                float v = acc[i][j][r] + bias; v = v > 0.f ? v : 0.f;
                out[(size_t)barr[j] * 524288 + o2 * 4096 + hwarr[j]] = v;
            }
        }
}

// ---------------- fill invalid (w < h) pixels with constant vector -----------
__global__ __launch_bounds__(256) void k_fill(const float* __restrict__ cvec,
                                              float* __restrict__ out) {
    int bo = blockIdx.x;
    float v = cvec[bo & 127];
    float* dst = out + (size_t)bo * 4096;
    for (int hw = threadIdx.x; hw < 4096; hw += 256) {
        int h = hw >> 6, w = hw & 63;
        if (w < h) dst[hw] = v;
    }
}

extern "C" void kernel_launch(void* const* d_in, const int* in_sizes, int n_in,
                              void* d_out, int out_size, void* d_ws, size_t ws_size,
                              hipStream_t stream) {
    const float* base = (const float*)d_in[0];
    const float* w1   = (const float*)d_in[1];
    const float* b1   = (const float*)d_in[2];
    const float* w3   = (const float*)d_in[3];
    const float* b3   = (const float*)d_in[4];
    const float* w2   = (const float*)d_in[5];
    const float* b2   = (const float*)d_in[6];
    const float* mask = (const float*)d_in[7];
    float* out = (float*)d_out;
    char* ws = (char*)d_ws;
    bf16*  xb     = (bf16*)(ws + OFF_XB);
    bf16*  w3b    = (bf16*)(ws + OFF_W3B);
    bf16*  w2b    = (bf16*)(ws + OFF_W2B);
    float* cvec   = (float*)(ws + OFF_CVEC);
    int*   pix2hw = (int*)(ws + OFF_PIX);
    bf16*  maskT  = (bf16*)(ws + OFF_MASKT);
    bf16*  x3     = (bf16*)(ws + OFF_X3);
    bf16*  bm     = (bf16*)(ws + OFF_BM);

    k_conv<<<dim3(32, 8), dim3(256), 0, stream>>>(base, w1, b1, xb);
    k_misc<<<dim3(2065), dim3(256), 0, stream>>>(w2, b2, b3, w3, w2b, w3b, cvec, pix2hw);
    k_maskT<<<dim3(33, 64), dim3(256), 0, stream>>>(mask, pix2hw, maskT);
    k_gemm2<<<dim3(4160), dim3(256), 0, stream>>>(maskT, xb, bm);
    k_gemm3<<<dim3(520), dim3(256), 0, stream>>>(w3b, bm, b3, x3);
    k_gemm4<<<dim3(260), dim3(256), 0, stream>>>(w2b, x3, b2, pix2hw, out);
    k_fill<<<dim3(1024), dim3(256), 0, stream>>>(cvec, out);
}